// Round 1
// baseline (440.597 us; speedup 1.0000x reference)
//
#include <hip/hip_runtime.h>
#include <hip/hip_bf16.h>
#include <math.h>

// ---------------------------------------------------------------------------
// HyperParamNet fused implementation (fp32, correctness-first round)
//
// Pipeline:
//   temp = interleave(y, mask) : (8, 56, 256, 256)   [never materialized]
//   t1 = relu(grouped conv3x3(temp, fw1, groups=28)) : 112 ch [never materialized]
//   t  = conv1x1(t1, fw2) + fb2 : 64 ch              [never materialized]
//   ta = t[:, :32]  -> spatial mean/max -> pgm MLP -> alpha (8)
//   tb = t[:, 32:]  -> per-pixel channel max/mean -> xc (8,2,256,256)
//   b1 = leaky(conv3x3(xc, bw1))   2->16
//   b2 = leaky(conv3x3(b1, bw2))  16->16
//   beta = sigmoid(conv3x3(b2, bw3)) 16->1  : (8,1,256,256)
// Output: [alpha(8) | beta(524288)]  fp32
// ---------------------------------------------------------------------------

__device__ __forceinline__ float leaky(float x) {
    return x >= 0.f ? x : 0.01f * x;
}

// ---------------------------------------------------------------------------
// Init: zero the ta-reduction accumulators (must run every call; ws is not
// re-poisoned between replays).
// ---------------------------------------------------------------------------
__global__ void kInit(float* __restrict__ sums, unsigned* __restrict__ maxu) {
    int t = threadIdx.x;   // 256 == 8*32
    sums[t] = 0.f;
    maxu[t] = 0u;          // transformed-uint 0 < any real float's key
}

// ---------------------------------------------------------------------------
// Kernel A: fused conv1(grouped 3x3) + relu + conv2(1x1) + tb channel
// max/mean (-> xc) + ta block-reduction (-> sums/maxu atomics).
// Grid: (16,16,8) tiles of 16x16 pixels; block 256 threads (1 thread/pixel).
// LDS: stages 28 of the 56 input channels at a time (18x18 halo tile).
// ---------------------------------------------------------------------------
__global__ __launch_bounds__(256) void kA(
    const float* __restrict__ y, const float* __restrict__ mask,
    const float* __restrict__ fw1, const float* __restrict__ fb1,
    const float* __restrict__ fw2, const float* __restrict__ fb2,
    float* __restrict__ xc, float* __restrict__ sums, unsigned* __restrict__ maxu)
{
    __shared__ float sh[28 * 324];   // 28 channels x 18x18 halo = 36288 B

    const int b  = blockIdx.z;
    const int h0 = blockIdx.y << 4;
    const int w0 = blockIdx.x << 4;
    const int tid = threadIdx.x;
    const int ty = tid >> 4, tx = tid & 15;

    float acc[64];
    #pragma unroll
    for (int o = 0; o < 64; ++o) acc[o] = fb2[o];

    #pragma unroll 1
    for (int half = 0; half < 2; ++half) {
        if (half) __syncthreads();   // previous compute must finish reading sh
        // ---- stage 28 temp-channels (14 groups) into LDS ----
        const int TOT = 28 * 324;
        for (int i = tid; i < TOT; i += 256) {
            int ch  = i / 324;              // local temp-channel 0..27
            int rem = i - ch * 324;
            int r   = rem / 18;
            int c   = rem - r * 18;
            int chg = half * 28 + ch;       // global temp-channel 0..55
            int g   = chg >> 1;             // group / original channel 0..27
            int gh = h0 + r - 1, gw = w0 + c - 1;
            float v = 0.f;
            if ((unsigned)gh < 256u && (unsigned)gw < 256u) {
                const float* src = (chg & 1) ? mask : y;
                v = src[(((size_t)b * 28 + g) << 16) + (gh << 8) + gw];
            }
            sh[i] = v;
        }
        __syncthreads();

        // ---- compute 14 groups ----
        #pragma unroll 1
        for (int gl = 0; gl < 14; ++gl) {
            const int g = half * 14 + gl;
            float r0 = fb1[4*g], r1 = fb1[4*g+1], r2 = fb1[4*g+2], r3 = fb1[4*g+3];
            const float* w1  = fw1 + (size_t)g * 72;        // 4 oc * 18 w each
            const float* shy = sh + (2*gl) * 324 + ty * 18 + tx;
            const float* shm = shy + 324;
            #pragma unroll
            for (int dy = 0; dy < 3; ++dy) {
                #pragma unroll
                for (int dx = 0; dx < 3; ++dx) {
                    float vy = shy[dy*18 + dx];
                    float vm = shm[dy*18 + dx];
                    int k = dy*3 + dx;
                    r0 += w1[     k]*vy + w1[ 9 + k]*vm;
                    r1 += w1[18 + k]*vy + w1[27 + k]*vm;
                    r2 += w1[36 + k]*vy + w1[45 + k]*vm;
                    r3 += w1[54 + k]*vy + w1[63 + k]*vm;
                }
            }
            r0 = fmaxf(r0, 0.f); r1 = fmaxf(r1, 0.f);
            r2 = fmaxf(r2, 0.f); r3 = fmaxf(r3, 0.f);
            const float* w2 = fw2 + 4*g;
            #pragma unroll
            for (int o = 0; o < 64; ++o) {
                const float* w2o = w2 + o * 112;
                acc[o] += w2o[0]*r0 + w2o[1]*r1 + w2o[2]*r2 + w2o[3]*r3;
            }
        }
    }

    const int h = h0 + ty, w = w0 + tx;

    // ---- tb (channels 32..63): per-pixel channel max & mean -> xc ----
    float tmax = acc[32], tsum = acc[32];
    #pragma unroll
    for (int o = 33; o < 64; ++o) { tmax = fmaxf(tmax, acc[o]); tsum += acc[o]; }
    xc[(((size_t)b*2 + 0) << 16) + (h << 8) + w] = tmax;
    xc[(((size_t)b*2 + 1) << 16) + (h << 8) + w] = tsum * (1.f/32.f);

    // ---- ta (channels 0..31): block reduce sum & max, then atomics ----
    __syncthreads();                 // done with sh; reuse as scratch
    float* red = sh;                 // [4 waves][32 ch][2]
    const int wave = tid >> 6, lane = tid & 63;
    #pragma unroll
    for (int c = 0; c < 32; ++c) {
        float s = acc[c], m = acc[c];
        #pragma unroll
        for (int off = 32; off > 0; off >>= 1) {
            s += __shfl_xor(s, off);
            m  = fmaxf(m, __shfl_xor(m, off));
        }
        if (lane == 0) {
            red[(wave*32 + c)*2 + 0] = s;
            red[(wave*32 + c)*2 + 1] = m;
        }
    }
    __syncthreads();
    if (tid < 32) {
        float s = red[tid*2] + red[(32+tid)*2] + red[(64+tid)*2] + red[(96+tid)*2];
        float m = fmaxf(fmaxf(red[tid*2+1], red[(32+tid)*2+1]),
                        fmaxf(red[(64+tid)*2+1], red[(96+tid)*2+1]));
        atomicAdd(&sums[b*32 + tid], s);
        unsigned ub  = __float_as_uint(m);
        unsigned key = (ub & 0x80000000u) ? ~ub : (ub | 0x80000000u);
        atomicMax(&maxu[b*32 + tid], key);
    }
}

// ---------------------------------------------------------------------------
// Kernel B: finish ta mean/max, run pgm MLP on both, alpha = sum.
// One block, 256 threads = 8 batches x 32 units.
// ---------------------------------------------------------------------------
__global__ __launch_bounds__(256) void kB(
    const float* __restrict__ sums, const unsigned* __restrict__ maxu,
    const float* __restrict__ aw1, const float* __restrict__ ab1,
    const float* __restrict__ aw2, const float* __restrict__ ab2,
    const float* __restrict__ aw3, const float* __restrict__ ab3,
    float* __restrict__ out)
{
    __shared__ float xa[8][32], xm[8][32], h1a[8][32], h1m[8][32];
    const int tid = threadIdx.x;
    const int b = tid >> 5, i = tid & 31;

    xa[b][i] = sums[b*32 + i] * (1.f/65536.f);
    unsigned u = maxu[b*32 + i];
    unsigned bits = (u & 0x80000000u) ? (u ^ 0x80000000u) : ~u;
    xm[b][i] = __uint_as_float(bits);
    __syncthreads();

    float sa = ab1[i], sm = ab1[i];
    #pragma unroll
    for (int j = 0; j < 32; ++j) {
        float w = aw1[i*32 + j];
        sa += w * xa[b][j]; sm += w * xm[b][j];
    }
    __syncthreads();
    h1a[b][i] = leaky(sa); h1m[b][i] = leaky(sm);
    __syncthreads();

    sa = ab2[i]; sm = ab2[i];
    #pragma unroll
    for (int j = 0; j < 32; ++j) {
        float w = aw2[i*32 + j];
        sa += w * h1a[b][j]; sm += w * h1m[b][j];
    }
    float h2a = leaky(sa), h2m = leaky(sm);

    float pa = aw3[i] * h2a, pm = aw3[i] * h2m;
    #pragma unroll
    for (int off = 16; off > 0; off >>= 1) {
        pa += __shfl_xor(pa, off);
        pm += __shfl_xor(pm, off);
    }
    if (i == 0) {
        float za = fmaxf(pa + ab3[0], 0.f) + 1e-6f;
        float zm = fmaxf(pm + ab3[0], 0.f) + 1e-6f;
        out[b] = za + zm;
    }
}

// ---------------------------------------------------------------------------
// Kernel C1: b1 = leaky(conv3x3(xc, bw1, bb1)), 2 -> 16 channels.
// ---------------------------------------------------------------------------
__global__ __launch_bounds__(256) void kC1(
    const float* __restrict__ xc, const float* __restrict__ bw1,
    const float* __restrict__ bb1, float* __restrict__ b1out)
{
    const int idx = blockIdx.x * 256 + threadIdx.x;
    const int b = idx >> 16, rem = idx & 65535;
    const int h = rem >> 8, w = rem & 255;
    float acc[16];
    #pragma unroll
    for (int o = 0; o < 16; ++o) acc[o] = bb1[o];
    #pragma unroll
    for (int ic = 0; ic < 2; ++ic) {
        const float* src = xc + (((size_t)b*2 + ic) << 16);
        #pragma unroll
        for (int dy = 0; dy < 3; ++dy) {
            int hh = h + dy - 1;
            #pragma unroll
            for (int dx = 0; dx < 3; ++dx) {
                int ww = w + dx - 1;
                float v = ((unsigned)hh < 256u && (unsigned)ww < 256u)
                          ? src[(hh << 8) + ww] : 0.f;
                int k = dy*3 + dx;
                #pragma unroll
                for (int o = 0; o < 16; ++o)
                    acc[o] += bw1[(o*2 + ic)*9 + k] * v;
            }
        }
    }
    #pragma unroll
    for (int o = 0; o < 16; ++o)
        b1out[(((size_t)b*16 + o) << 16) + rem] = leaky(acc[o]);
}

// ---------------------------------------------------------------------------
// Kernel C2: b2 = leaky(conv3x3(b1, bw2, bb2)), 16 -> 16 channels.
// ---------------------------------------------------------------------------
__global__ __launch_bounds__(256) void kC2(
    const float* __restrict__ b1in, const float* __restrict__ bw2,
    const float* __restrict__ bb2, float* __restrict__ b2out)
{
    const int idx = blockIdx.x * 256 + threadIdx.x;
    const int b = idx >> 16, rem = idx & 65535;
    const int h = rem >> 8, w = rem & 255;
    float acc[16];
    #pragma unroll
    for (int o = 0; o < 16; ++o) acc[o] = bb2[o];
    #pragma unroll 1
    for (int ic = 0; ic < 16; ++ic) {
        const float* src = b1in + (((size_t)b*16 + ic) << 16);
        #pragma unroll
        for (int dy = 0; dy < 3; ++dy) {
            int hh = h + dy - 1;
            #pragma unroll
            for (int dx = 0; dx < 3; ++dx) {
                int ww = w + dx - 1;
                float v = ((unsigned)hh < 256u && (unsigned)ww < 256u)
                          ? src[(hh << 8) + ww] : 0.f;
                int k = dy*3 + dx;
                #pragma unroll
                for (int o = 0; o < 16; ++o)
                    acc[o] += bw2[(o*16 + ic)*9 + k] * v;
            }
        }
    }
    #pragma unroll
    for (int o = 0; o < 16; ++o)
        b2out[(((size_t)b*16 + o) << 16) + rem] = leaky(acc[o]);
}

// ---------------------------------------------------------------------------
// Kernel C3: beta = sigmoid(conv3x3(b2, bw3, bb3)), 16 -> 1 channel.
// ---------------------------------------------------------------------------
__global__ __launch_bounds__(256) void kC3(
    const float* __restrict__ b2in, const float* __restrict__ bw3,
    const float* __restrict__ bb3, float* __restrict__ betaout)
{
    const int idx = blockIdx.x * 256 + threadIdx.x;
    const int b = idx >> 16, rem = idx & 65535;
    const int h = rem >> 8, w = rem & 255;
    float acc = bb3[0];
    #pragma unroll 1
    for (int ic = 0; ic < 16; ++ic) {
        const float* src = b2in + (((size_t)b*16 + ic) << 16);
        #pragma unroll
        for (int dy = 0; dy < 3; ++dy) {
            int hh = h + dy - 1;
            #pragma unroll
            for (int dx = 0; dx < 3; ++dx) {
                int ww = w + dx - 1;
                float v = ((unsigned)hh < 256u && (unsigned)ww < 256u)
                          ? src[(hh << 8) + ww] : 0.f;
                acc += bw3[ic*9 + dy*3 + dx] * v;
            }
        }
    }
    betaout[idx] = 1.f / (1.f + expf(-acc));
}

// ---------------------------------------------------------------------------
extern "C" void kernel_launch(void* const* d_in, const int* in_sizes, int n_in,
                              void* d_out, int out_size, void* d_ws, size_t ws_size,
                              hipStream_t stream) {
    const float* y    = (const float*)d_in[0];
    const float* mask = (const float*)d_in[1];
    const float* fw1  = (const float*)d_in[2];
    const float* fb1  = (const float*)d_in[3];
    const float* fw2  = (const float*)d_in[4];
    const float* fb2  = (const float*)d_in[5];
    const float* aw1  = (const float*)d_in[6];
    const float* ab1  = (const float*)d_in[7];
    const float* aw2  = (const float*)d_in[8];
    const float* ab2  = (const float*)d_in[9];
    const float* aw3  = (const float*)d_in[10];
    const float* ab3  = (const float*)d_in[11];
    const float* bw1  = (const float*)d_in[12];
    const float* bb1  = (const float*)d_in[13];
    const float* bw2  = (const float*)d_in[14];
    const float* bb2  = (const float*)d_in[15];
    const float* bw3  = (const float*)d_in[16];
    const float* bb3  = (const float*)d_in[17];
    float* out = (float*)d_out;

    char* ws = (char*)d_ws;
    float*    sums = (float*)ws;                               // 1 KB
    unsigned* maxu = (unsigned*)(ws + 1024);                   // 1 KB
    float*    xc   = (float*)(ws + 4096);                      // 4 MB
    float*    b1   = (float*)(ws + 4096 + 4194304);            // 33.5 MB
    float*    b2   = (float*)(ws + 4096 + 4194304 + 33554432); // 33.5 MB

    kInit<<<1, 256, 0, stream>>>(sums, maxu);
    kA<<<dim3(16, 16, 8), 256, 0, stream>>>(y, mask, fw1, fb1, fw2, fb2,
                                            xc, sums, maxu);
    kB<<<1, 256, 0, stream>>>(sums, maxu, aw1, ab1, aw2, ab2, aw3, ab3, out);
    kC1<<<2048, 256, 0, stream>>>(xc, bw1, bb1, b1);
    kC2<<<2048, 256, 0, stream>>>(b1, bw2, bb2, b2);
    kC3<<<2048, 256, 0, stream>>>(b2, bw3, bb3, out + 8);
}

// Round 2
// 403.874 us; speedup vs baseline: 1.0909x; 1.0909x over previous
//
#include <hip/hip_runtime.h>
#include <hip/hip_bf16.h>
#include <math.h>

// ---------------------------------------------------------------------------
// HyperParamNet fused implementation — round 2.
// Changes vs round 1 (all in kA, the 389/440 us hotspot):
//   * __launch_bounds__(256,1): round-1 build showed VGPR_Count=52 with
//     acc[64] -> compiler had pushed accumulators to AGPRs (accvgpr
//     read/write churn on every conv2 FMA). Full VGPR budget fixes that.
//   * y/mask staged interleaved as float2 -> 9 ds_read_b64 per group
//     (was 18 ds_read_b32) and a conflict-free wave64 access pattern
//     (row-group word-bases 0/36/72/108 = banks 0/4/8/12 mod 32).
// ---------------------------------------------------------------------------

__device__ __forceinline__ float leaky(float x) {
    return x >= 0.f ? x : 0.01f * x;
}

// ---------------------------------------------------------------------------
__global__ void kInit(float* __restrict__ sums, unsigned* __restrict__ maxu) {
    int t = threadIdx.x;   // 256 == 8*32
    sums[t] = 0.f;
    maxu[t] = 0u;
}

// ---------------------------------------------------------------------------
// Kernel A: fused conv1(grouped 3x3) + relu + conv2(1x1) + tb channel
// max/mean (-> xc) + ta block-reduction (-> sums/maxu atomics).
// Grid: (16,16,8) tiles of 16x16 pixels; block 256 threads (1 thread/pixel).
// LDS: stages 14 groups (28 temp-channels) at a time as float2 (y,mask).
// ---------------------------------------------------------------------------
__global__ __launch_bounds__(256, 1) void kA(
    const float* __restrict__ y, const float* __restrict__ mask,
    const float* __restrict__ fw1, const float* __restrict__ fb1,
    const float* __restrict__ fw2, const float* __restrict__ fb2,
    float* __restrict__ xc, float* __restrict__ sums, unsigned* __restrict__ maxu)
{
    __shared__ float2 sh[14 * 324];   // 14 groups x 18x18 halo x (y,mask) = 36288 B

    const int b  = blockIdx.z;
    const int h0 = blockIdx.y << 4;
    const int w0 = blockIdx.x << 4;
    const int tid = threadIdx.x;
    const int ty = tid >> 4, tx = tid & 15;

    float acc[64];
    #pragma unroll
    for (int o = 0; o < 64; ++o) acc[o] = fb2[o];

    #pragma unroll 1
    for (int half = 0; half < 2; ++half) {
        if (half) __syncthreads();   // previous compute must finish reading sh
        // ---- stage 14 groups into LDS as (y,mask) float2 ----
        const int TOT = 14 * 324;
        for (int i = tid; i < TOT; i += 256) {
            int gl  = i / 324;              // local group 0..13
            int rem = i - gl * 324;
            int r   = rem / 18;
            int c   = rem - r * 18;
            int oc  = half * 14 + gl;       // original channel / group 0..27
            int gh = h0 + r - 1, gw = w0 + c - 1;
            float2 v = make_float2(0.f, 0.f);
            if ((unsigned)gh < 256u && (unsigned)gw < 256u) {
                size_t off = (((size_t)b * 28 + oc) << 16) + (gh << 8) + gw;
                v.x = y[off];
                v.y = mask[off];
            }
            sh[i] = v;
        }
        __syncthreads();

        // ---- compute 14 groups ----
        #pragma unroll 1
        for (int gl = 0; gl < 14; ++gl) {
            const int g = half * 14 + gl;
            float r0 = fb1[4*g], r1 = fb1[4*g+1], r2 = fb1[4*g+2], r3 = fb1[4*g+3];
            const float* w1 = fw1 + (size_t)g * 72;      // 4 oc * 18 w each
            const float2* shp = sh + gl * 324 + ty * 18 + tx;
            #pragma unroll
            for (int dy = 0; dy < 3; ++dy) {
                #pragma unroll
                for (int dx = 0; dx < 3; ++dx) {
                    float2 v = shp[dy*18 + dx];
                    int k = dy*3 + dx;
                    r0 += w1[     k]*v.x + w1[ 9 + k]*v.y;
                    r1 += w1[18 + k]*v.x + w1[27 + k]*v.y;
                    r2 += w1[36 + k]*v.x + w1[45 + k]*v.y;
                    r3 += w1[54 + k]*v.x + w1[63 + k]*v.y;
                }
            }
            r0 = fmaxf(r0, 0.f); r1 = fmaxf(r1, 0.f);
            r2 = fmaxf(r2, 0.f); r3 = fmaxf(r3, 0.f);
            const float* w2 = fw2 + 4*g;
            #pragma unroll
            for (int o = 0; o < 64; ++o) {
                const float* w2o = w2 + o * 112;
                acc[o] += w2o[0]*r0 + w2o[1]*r1 + w2o[2]*r2 + w2o[3]*r3;
            }
        }
    }

    const int h = h0 + ty, w = w0 + tx;

    // ---- tb (channels 32..63): per-pixel channel max & mean -> xc ----
    float tmax = acc[32], tsum = acc[32];
    #pragma unroll
    for (int o = 33; o < 64; ++o) { tmax = fmaxf(tmax, acc[o]); tsum += acc[o]; }
    xc[(((size_t)b*2 + 0) << 16) + (h << 8) + w] = tmax;
    xc[(((size_t)b*2 + 1) << 16) + (h << 8) + w] = tsum * (1.f/32.f);

    // ---- ta (channels 0..31): block reduce sum & max, then atomics ----
    __syncthreads();                 // done with sh; reuse as scratch
    float* red = (float*)sh;         // [4 waves][32 ch][2]
    const int wave = tid >> 6, lane = tid & 63;
    #pragma unroll
    for (int c = 0; c < 32; ++c) {
        float s = acc[c], m = acc[c];
        #pragma unroll
        for (int off = 32; off > 0; off >>= 1) {
            s += __shfl_xor(s, off);
            m  = fmaxf(m, __shfl_xor(m, off));
        }
        if (lane == 0) {
            red[(wave*32 + c)*2 + 0] = s;
            red[(wave*32 + c)*2 + 1] = m;
        }
    }
    __syncthreads();
    if (tid < 32) {
        float s = red[tid*2] + red[(32+tid)*2] + red[(64+tid)*2] + red[(96+tid)*2];
        float m = fmaxf(fmaxf(red[tid*2+1], red[(32+tid)*2+1]),
                        fmaxf(red[(64+tid)*2+1], red[(96+tid)*2+1]));
        atomicAdd(&sums[b*32 + tid], s);
        unsigned ub  = __float_as_uint(m);
        unsigned key = (ub & 0x80000000u) ? ~ub : (ub | 0x80000000u);
        atomicMax(&maxu[b*32 + tid], key);
    }
}

// ---------------------------------------------------------------------------
// Kernel B: finish ta mean/max, run pgm MLP on both, alpha = sum.
// ---------------------------------------------------------------------------
__global__ __launch_bounds__(256) void kB(
    const float* __restrict__ sums, const unsigned* __restrict__ maxu,
    const float* __restrict__ aw1, const float* __restrict__ ab1,
    const float* __restrict__ aw2, const float* __restrict__ ab2,
    const float* __restrict__ aw3, const float* __restrict__ ab3,
    float* __restrict__ out)
{
    __shared__ float xa[8][32], xm[8][32], h1a[8][32], h1m[8][32];
    const int tid = threadIdx.x;
    const int b = tid >> 5, i = tid & 31;

    xa[b][i] = sums[b*32 + i] * (1.f/65536.f);
    unsigned u = maxu[b*32 + i];
    unsigned bits = (u & 0x80000000u) ? (u ^ 0x80000000u) : ~u;
    xm[b][i] = __uint_as_float(bits);
    __syncthreads();

    float sa = ab1[i], sm = ab1[i];
    #pragma unroll
    for (int j = 0; j < 32; ++j) {
        float w = aw1[i*32 + j];
        sa += w * xa[b][j]; sm += w * xm[b][j];
    }
    __syncthreads();
    h1a[b][i] = leaky(sa); h1m[b][i] = leaky(sm);
    __syncthreads();

    sa = ab2[i]; sm = ab2[i];
    #pragma unroll
    for (int j = 0; j < 32; ++j) {
        float w = aw2[i*32 + j];
        sa += w * h1a[b][j]; sm += w * h1m[b][j];
    }
    float h2a = leaky(sa), h2m = leaky(sm);

    float pa = aw3[i] * h2a, pm = aw3[i] * h2m;
    #pragma unroll
    for (int off = 16; off > 0; off >>= 1) {
        pa += __shfl_xor(pa, off);
        pm += __shfl_xor(pm, off);
    }
    if (i == 0) {
        float za = fmaxf(pa + ab3[0], 0.f) + 1e-6f;
        float zm = fmaxf(pm + ab3[0], 0.f) + 1e-6f;
        out[b] = za + zm;
    }
}

// ---------------------------------------------------------------------------
// Kernel C1: b1 = leaky(conv3x3(xc, bw1, bb1)), 2 -> 16 channels.
// ---------------------------------------------------------------------------
__global__ __launch_bounds__(256) void kC1(
    const float* __restrict__ xc, const float* __restrict__ bw1,
    const float* __restrict__ bb1, float* __restrict__ b1out)
{
    const int idx = blockIdx.x * 256 + threadIdx.x;
    const int b = idx >> 16, rem = idx & 65535;
    const int h = rem >> 8, w = rem & 255;
    float acc[16];
    #pragma unroll
    for (int o = 0; o < 16; ++o) acc[o] = bb1[o];
    #pragma unroll
    for (int ic = 0; ic < 2; ++ic) {
        const float* src = xc + (((size_t)b*2 + ic) << 16);
        #pragma unroll
        for (int dy = 0; dy < 3; ++dy) {
            int hh = h + dy - 1;
            #pragma unroll
            for (int dx = 0; dx < 3; ++dx) {
                int ww = w + dx - 1;
                float v = ((unsigned)hh < 256u && (unsigned)ww < 256u)
                          ? src[(hh << 8) + ww] : 0.f;
                int k = dy*3 + dx;
                #pragma unroll
                for (int o = 0; o < 16; ++o)
                    acc[o] += bw1[(o*2 + ic)*9 + k] * v;
            }
        }
    }
    #pragma unroll
    for (int o = 0; o < 16; ++o)
        b1out[(((size_t)b*16 + o) << 16) + rem] = leaky(acc[o]);
}

// ---------------------------------------------------------------------------
// Kernel C2: b2 = leaky(conv3x3(b1, bw2, bb2)), 16 -> 16 channels.
// ---------------------------------------------------------------------------
__global__ __launch_bounds__(256) void kC2(
    const float* __restrict__ b1in, const float* __restrict__ bw2,
    const float* __restrict__ bb2, float* __restrict__ b2out)
{
    const int idx = blockIdx.x * 256 + threadIdx.x;
    const int b = idx >> 16, rem = idx & 65535;
    const int h = rem >> 8, w = rem & 255;
    float acc[16];
    #pragma unroll
    for (int o = 0; o < 16; ++o) acc[o] = bb2[o];
    #pragma unroll 1
    for (int ic = 0; ic < 16; ++ic) {
        const float* src = b1in + (((size_t)b*16 + ic) << 16);
        #pragma unroll
        for (int dy = 0; dy < 3; ++dy) {
            int hh = h + dy - 1;
            #pragma unroll
            for (int dx = 0; dx < 3; ++dx) {
                int ww = w + dx - 1;
                float v = ((unsigned)hh < 256u && (unsigned)ww < 256u)
                          ? src[(hh << 8) + ww] : 0.f;
                int k = dy*3 + dx;
                #pragma unroll
                for (int o = 0; o < 16; ++o)
                    acc[o] += bw2[(o*16 + ic)*9 + k] * v;
            }
        }
    }
    #pragma unroll
    for (int o = 0; o < 16; ++o)
        b2out[(((size_t)b*16 + o) << 16) + rem] = leaky(acc[o]);
}

// ---------------------------------------------------------------------------
// Kernel C3: beta = sigmoid(conv3x3(b2, bw3, bb3)), 16 -> 1 channel.
// ---------------------------------------------------------------------------
__global__ __launch_bounds__(256) void kC3(
    const float* __restrict__ b2in, const float* __restrict__ bw3,
    const float* __restrict__ bb3, float* __restrict__ betaout)
{
    const int idx = blockIdx.x * 256 + threadIdx.x;
    const int b = idx >> 16, rem = idx & 65535;
    const int h = rem >> 8, w = rem & 255;
    float acc = bb3[0];
    #pragma unroll 1
    for (int ic = 0; ic < 16; ++ic) {
        const float* src = b2in + (((size_t)b*16 + ic) << 16);
        #pragma unroll
        for (int dy = 0; dy < 3; ++dy) {
            int hh = h + dy - 1;
            #pragma unroll
            for (int dx = 0; dx < 3; ++dx) {
                int ww = w + dx - 1;
                float v = ((unsigned)hh < 256u && (unsigned)ww < 256u)
                          ? src[(hh << 8) + ww] : 0.f;
                acc += bw3[ic*9 + dy*3 + dx] * v;
            }
        }
    }
    betaout[idx] = 1.f / (1.f + expf(-acc));
}

// ---------------------------------------------------------------------------
extern "C" void kernel_launch(void* const* d_in, const int* in_sizes, int n_in,
                              void* d_out, int out_size, void* d_ws, size_t ws_size,
                              hipStream_t stream) {
    const float* y    = (const float*)d_in[0];
    const float* mask = (const float*)d_in[1];
    const float* fw1  = (const float*)d_in[2];
    const float* fb1  = (const float*)d_in[3];
    const float* fw2  = (const float*)d_in[4];
    const float* fb2  = (const float*)d_in[5];
    const float* aw1  = (const float*)d_in[6];
    const float* ab1  = (const float*)d_in[7];
    const float* aw2  = (const float*)d_in[8];
    const float* ab2  = (const float*)d_in[9];
    const float* aw3  = (const float*)d_in[10];
    const float* ab3  = (const float*)d_in[11];
    const float* bw1  = (const float*)d_in[12];
    const float* bb1  = (const float*)d_in[13];
    const float* bw2  = (const float*)d_in[14];
    const float* bb2  = (const float*)d_in[15];
    const float* bw3  = (const float*)d_in[16];
    const float* bb3  = (const float*)d_in[17];
    float* out = (float*)d_out;

    char* ws = (char*)d_ws;
    float*    sums = (float*)ws;                               // 1 KB
    unsigned* maxu = (unsigned*)(ws + 1024);                   // 1 KB
    float*    xc   = (float*)(ws + 4096);                      // 4 MB
    float*    b1   = (float*)(ws + 4096 + 4194304);            // 33.5 MB
    float*    b2   = (float*)(ws + 4096 + 4194304 + 33554432); // 33.5 MB

    kInit<<<1, 256, 0, stream>>>(sums, maxu);
    kA<<<dim3(16, 16, 8), 256, 0, stream>>>(y, mask, fw1, fb1, fw2, fb2,
                                            xc, sums, maxu);
    kB<<<1, 256, 0, stream>>>(sums, maxu, aw1, ab1, aw2, ab2, aw3, ab3, out);
    kC1<<<2048, 256, 0, stream>>>(xc, bw1, bb1, b1);
    kC2<<<2048, 256, 0, stream>>>(b1, bw2, bb2, b2);
    kC3<<<2048, 256, 0, stream>>>(b2, bw3, bb3, out + 8);
}